// Round 2
// baseline (21521.802 us; speedup 1.0000x reference)
//
#include <hip/hip_runtime.h>
#include <hip/hip_bf16.h>
#include <hip/hip_fp16.h>

#define TT 2048
#define BB 64
#define HH 512
#define GG 2048  // 4H

typedef __attribute__((ext_vector_type(4))) float f32x4;
typedef __attribute__((ext_vector_type(8))) short short8;
typedef __attribute__((ext_vector_type(4))) short short4v;

static __device__ __forceinline__ short f2bf(float f) {
  unsigned u = __builtin_bit_cast(unsigned, f);
  u = (u + 0x7FFFu + ((u >> 16) & 1u)) >> 16;
  return (short)u;
}
static __device__ __forceinline__ float fsigmoid(float x) { return 1.0f / (1.0f + __expf(-x)); }
static __device__ __forceinline__ float ftanh(float x) {
  float e = __expf(2.0f * x);
  return 1.0f - 2.0f / (e + 1.0f);
}
static __device__ __forceinline__ float h2f(unsigned short u) {
  __half h = __builtin_bit_cast(__half, u);
  return __half2float(h);
}

// ---------------- fp32 -> bf16 convert ----------------
__global__ void cvt_bf16_kernel(const float4* __restrict__ in, short4v* __restrict__ outp, long n4) {
  long i = (long)blockIdx.x * blockDim.x + threadIdx.x;
  long stride = (long)gridDim.x * blockDim.x;
  for (; i < n4; i += stride) {
    float4 v = in[i];
    short4v o;
    o[0] = f2bf(v.x); o[1] = f2bf(v.y); o[2] = f2bf(v.z); o[3] = f2bf(v.w);
    outp[i] = o;
  }
}

// ---------------- phase 1: xpart = X @ W_ih^T + (b_ih + b_hh), f16 out ----------------
__global__ __launch_bounds__(256) void gemm_xpart(
    const __hip_bfloat16* __restrict__ Abf, const __hip_bfloat16* __restrict__ Bbf,
    const float* __restrict__ bih, const float* __restrict__ bhh, __half* __restrict__ xout) {
  __shared__ __hip_bfloat16 As[128 * 64];
  __shared__ __hip_bfloat16 Bs[128 * 64];
  const int nwg = gridDim.x;
  const int bid = blockIdx.x;
  const int vb = (bid & 7) * (nwg >> 3) + (bid >> 3);
  const int mt = vb >> 4;
  const int nt = vb & 15;
  const size_t m0 = (size_t)mt * 128;
  const int n0 = nt * 128;
  const int tid = threadIdx.x;
  const int lane = tid & 63;
  const int w = tid >> 6;
  const int wm = w >> 1, wn = w & 1;
  const int g = lane >> 4;
  f32x4 acc[4][4] = {};
  for (int k0 = 0; k0 < 512; k0 += 64) {
#pragma unroll
    for (int i = 0; i < 4; i++) {
      const int slot = w * 4 + i;
      const int row = slot * 8 + (lane >> 3);
      const int segS = (lane & 7) ^ (row & 7);
      const __hip_bfloat16* ga = Abf + (m0 + row) * 512 + k0 + segS * 8;
      const __hip_bfloat16* gb = Bbf + (size_t)(n0 + row) * 512 + k0 + segS * 8;
      __builtin_amdgcn_global_load_lds(
          (const __attribute__((address_space(1))) unsigned*)(const void*)ga,
          (__attribute__((address_space(3))) unsigned*)(void*)(As + slot * 512), 16, 0, 0);
      __builtin_amdgcn_global_load_lds(
          (const __attribute__((address_space(1))) unsigned*)(const void*)gb,
          (__attribute__((address_space(3))) unsigned*)(void*)(Bs + slot * 512), 16, 0, 0);
    }
    __syncthreads();
#pragma unroll
    for (int kk = 0; kk < 2; kk++) {
      short8 av[4], bv[4];
#pragma unroll
      for (int f = 0; f < 4; f++) {
        const int row = wm * 64 + f * 16 + (lane & 15);
        av[f] = *(const short8*)(As + row * 64 + ((((kk << 2) + g) ^ (row & 7)) << 3));
      }
#pragma unroll
      for (int f = 0; f < 4; f++) {
        const int row = wn * 64 + f * 16 + (lane & 15);
        bv[f] = *(const short8*)(Bs + row * 64 + ((((kk << 2) + g) ^ (row & 7)) << 3));
      }
#pragma unroll
      for (int fi = 0; fi < 4; fi++)
#pragma unroll
        for (int fj = 0; fj < 4; fj++)
          acc[fi][fj] = __builtin_amdgcn_mfma_f32_16x16x32_bf16(av[fi], bv[fj], acc[fi][fj], 0, 0, 0);
    }
    __syncthreads();
  }
#pragma unroll
  for (int fj = 0; fj < 4; fj++) {
    const int n = n0 + wn * 64 + fj * 16 + (lane & 15);
    const float bias = bih[n] + bhh[n];
#pragma unroll
    for (int fi = 0; fi < 4; fi++) {
      const size_t mrow = m0 + wm * 64 + fi * 16 + g * 4;
#pragma unroll
      for (int r = 0; r < 4; r++) {
        const float vv = acc[fi][fj][r] + bias;
        xout[(mrow + r) * GG + n] = __float2half(vv);
      }
    }
  }
}

// ---------------- phase 2: persistent LSTM scan, W_hh in registers ----------------
// 32 blocks x 512 threads (8 waves). Block owns 16 h-cols (64 gate rows, gate-interleaved
// so each lane's acc f32x4 = {i,f,g,o} of one (batch, hcol) cell).
// Wave w: nt = w&3 (batches nt*16..+16), M-tiles {w>>2, (w>>2)+2} (hcols mt*4+g4).
// Cross-block h exchange: relaxed AGENT-scope atomics (coherence point), no cache fences.
__global__ __launch_bounds__(512, 2) void lstm_scan_kernel(
    const __half* __restrict__ xpart, const float* __restrict__ Whh,
    unsigned long long* hbuf, float* __restrict__ outp, unsigned* counter) {
  __shared__ unsigned short xps[2][4096];  // [buf][batch(64)][8 chunks x 8 f16], chunk^=(b&7)
  const int blk = blockIdx.x;
  const int tid = threadIdx.x;
  const int lane = tid & 63;
  const int w = tid >> 6;
  const int b16 = lane & 15;
  const int g4 = lane >> 4;
  const int nt = w & 3;
  const int mtA = w >> 2;       // 0 or 1
  const int mtB = mtA + 2;      // 2 or 3
  const int batch = nt * 16 + b16;
  const int qr = b16 & 3;       // A-frag row -> gate
  const int jj = b16 >> 2;      // A-frag row -> hcol-in-tile
  const int colA = blk * 16 + mtA * 4 + g4;
  const int colB = blk * 16 + mtB * 4 + g4;

  // ---- one-time: W_hh slices -> registers (bf16 frags) ----
  const int rowA = qr * 512 + blk * 16 + mtA * 4 + jj;
  const int rowB = qr * 512 + blk * 16 + mtB * 4 + jj;
  short8 wA[16], wB[16];
#pragma unroll
  for (int kt = 0; kt < 16; kt++) {
    const float* pa = Whh + (size_t)rowA * 512 + kt * 32 + g4 * 8;
    const float* pb = Whh + (size_t)rowB * 512 + kt * 32 + g4 * 8;
    float4 a0 = *(const float4*)pa;
    float4 a1 = *(const float4*)(pa + 4);
    float4 b0 = *(const float4*)pb;
    float4 b1 = *(const float4*)(pb + 4);
    short8 va, vb;
    va[0] = f2bf(a0.x); va[1] = f2bf(a0.y); va[2] = f2bf(a0.z); va[3] = f2bf(a0.w);
    va[4] = f2bf(a1.x); va[5] = f2bf(a1.y); va[6] = f2bf(a1.z); va[7] = f2bf(a1.w);
    vb[0] = f2bf(b0.x); vb[1] = f2bf(b0.y); vb[2] = f2bf(b0.z); vb[3] = f2bf(b0.w);
    vb[4] = f2bf(b1.x); vb[5] = f2bf(b1.y); vb[6] = f2bf(b1.z); vb[7] = f2bf(b1.w);
    wA[kt] = va;
    wB[kt] = vb;
  }

  // ---- xpart staging assignment: thread -> (batch sb, 16B chunk sch) ----
  const int sb = tid >> 3;
  const int sch = tid & 7;
  const int schS = sch ^ (sb & 7);
  char* xpsb = (char*)&xps[0][0];
  {  // prologue: tile t=0 into buf0
    const __half* src = xpart + (size_t)sb * GG + (sch >> 1) * 512 + blk * 16 + (sch & 1) * 8;
    short8 v = *(const short8*)(const void*)src;
    *(short8*)(xpsb + sb * 128 + schS * 16) = v;
  }
  __syncthreads();

  float cA = 0.f, cB = 0.f, hAv = 0.f, hBv = 0.f;

  for (int t = 0; t < TT; t++) {
    // 1. issue next-step xpart load early (hides under poll + MFMA)
    const int tn = (t + 1 < TT) ? (t + 1) : (TT - 1);
    const __half* src = xpart + ((size_t)tn * BB + sb) * GG + (sch >> 1) * 512 + blk * 16 + (sch & 1) * 8;
    short8 xv = *(const short8*)(const void*)src;

    // 2. wait: all 32 blocks completed step t-1 (single MALL counter, relaxed poll)
    if (t > 0) {
      const unsigned need = (unsigned)(32 * t);
      if (lane == 0) {
        while (__hip_atomic_load(counter, __ATOMIC_RELAXED, __HIP_MEMORY_SCOPE_AGENT) < need) {
        }
      }
    }

    // 3. B-frags: h_t direct to registers via relaxed agent atomic 8B loads
    const unsigned long long* hp =
        hbuf + (size_t)(t & 1) * (BB * 128) + (size_t)batch * 128 + g4 * 2;
    short4v hlo[16], hhi[16];
#pragma unroll
    for (int kt = 0; kt < 16; kt++) {
      unsigned long long u0 = __hip_atomic_load(hp + kt * 8, __ATOMIC_RELAXED, __HIP_MEMORY_SCOPE_AGENT);
      unsigned long long u1 = __hip_atomic_load(hp + kt * 8 + 1, __ATOMIC_RELAXED, __HIP_MEMORY_SCOPE_AGENT);
      hlo[kt] = __builtin_bit_cast(short4v, u0);
      hhi[kt] = __builtin_bit_cast(short4v, u1);
    }

    // 4. MFMA: 2 independent chains
    f32x4 accA = {0.f, 0.f, 0.f, 0.f};
    f32x4 accB = {0.f, 0.f, 0.f, 0.f};
#pragma unroll
    for (int kt = 0; kt < 16; kt++) {
      short8 hf;
      hf[0] = hlo[kt][0]; hf[1] = hlo[kt][1]; hf[2] = hlo[kt][2]; hf[3] = hlo[kt][3];
      hf[4] = hhi[kt][0]; hf[5] = hhi[kt][1]; hf[6] = hhi[kt][2]; hf[7] = hhi[kt][3];
      accA = __builtin_amdgcn_mfma_f32_16x16x32_bf16(wA[kt], hf, accA, 0, 0, 0);
      accB = __builtin_amdgcn_mfma_f32_16x16x32_bf16(wB[kt], hf, accB, 0, 0, 0);
    }

    // 5. pointwise: xpart from LDS (swizzled), acc reg r = gate r
    const char* xb = xpsb + (t & 1) * 8192 + batch * 128;
    const int bx = batch & 7;
    float xA[4], xB[4];
#pragma unroll
    for (int qq = 0; qq < 4; qq++) {
      unsigned short uA = *(const unsigned short*)(xb + (((qq * 2) ^ bx) << 4) + ((colA & 7) << 1));
      unsigned short uB = *(const unsigned short*)(xb + (((qq * 2 + 1) ^ bx) << 4) + ((colB & 7) << 1));
      xA[qq] = h2f(uA);
      xB[qq] = h2f(uB);
    }
    float iA = fsigmoid(accA[0] + xA[0]);
    float fA = fsigmoid(accA[1] + xA[1]);
    float gA = ftanh(accA[2] + xA[2]);
    float oA = fsigmoid(accA[3] + xA[3]);
    cA = fA * cA + iA * gA;
    hAv = oA * ftanh(cA);
    float iB = fsigmoid(accB[0] + xB[0]);
    float fB = fsigmoid(accB[1] + xB[1]);
    float gB = ftanh(accB[2] + xB[2]);
    float oB = fsigmoid(accB[3] + xB[3]);
    cB = fB * cB + iB * gB;
    hBv = oB * ftanh(cB);

    // 6. commit prefetched xpart tile (consumed after next barrier)
    *(short8*)(xpsb + ((t + 1) & 1) * 8192 + sb * 128 + schS * 16) = xv;

    // 7. outputs (plain cached) + h_{t+1} (relaxed agent atomic dword, bf16x2 packed)
    float hAp = __shfl_xor(hAv, 16, 64);
    float hBp = __shfl_xor(hBv, 16, 64);
    float* od = outp + ((size_t)t * BB + batch) * HH;
    od[colA] = hAv;
    od[colB] = hBv;
    if ((g4 & 1) == 0) {
      unsigned* hd = (unsigned*)(hbuf + (size_t)((t + 1) & 1) * (BB * 128));
      unsigned pkA = (unsigned)(unsigned short)f2bf(hAv) | ((unsigned)(unsigned short)f2bf(hAp) << 16);
      unsigned pkB = (unsigned)(unsigned short)f2bf(hBv) | ((unsigned)(unsigned short)f2bf(hBp) << 16);
      __hip_atomic_store(hd + (size_t)batch * 256 + (colA >> 1), pkA, __ATOMIC_RELAXED, __HIP_MEMORY_SCOPE_AGENT);
      __hip_atomic_store(hd + (size_t)batch * 256 + (colB >> 1), pkB, __ATOMIC_RELAXED, __HIP_MEMORY_SCOPE_AGENT);
    }

    // 8. all stores at coherence point -> signal
    asm volatile("s_waitcnt vmcnt(0)" ::: "memory");
    __syncthreads();
    if (tid == 0) __hip_atomic_fetch_add(counter, 1u, __ATOMIC_RELAXED, __HIP_MEMORY_SCOPE_AGENT);
  }

  // final (h_T, c_T)
  float* hT = outp + (size_t)TT * BB * HH;
  float* cT = hT + (size_t)BB * HH;
  hT[(size_t)batch * HH + colA] = hAv;
  hT[(size_t)batch * HH + colB] = hBv;
  cT[(size_t)batch * HH + colA] = cA;
  cT[(size_t)batch * HH + colB] = cB;
}

extern "C" void kernel_launch(void* const* d_in, const int* in_sizes, int n_in,
                              void* d_out, int out_size, void* d_ws, size_t ws_size,
                              hipStream_t stream) {
  (void)in_sizes; (void)n_in; (void)out_size; (void)ws_size;
  const float* x = (const float*)d_in[0];
  const float* Wih = (const float*)d_in[1];
  const float* Whh = (const float*)d_in[2];
  const float* bih = (const float*)d_in[3];
  const float* bhh = (const float*)d_in[4];
  float* outp = (float*)d_out;
  char* ws = (char*)d_ws;

  const size_t M = (size_t)TT * BB;  // 131072
  size_t off = 0;
  auto take = [&](size_t sz) { size_t r = off; off = (off + sz + 255) & ~255ULL; return r; };
  const size_t xbf_o = take(M * 512 * 2);
  const size_t wih_o = take((size_t)GG * 512 * 2);
  const size_t hbuf_o = take(2 * (size_t)BB * HH * 2);
  const size_t cnt_o = take(256);
  const size_t xpart_o = take(M * (size_t)GG * 2);

  __hip_bfloat16* xbf = (__hip_bfloat16*)(ws + xbf_o);
  __hip_bfloat16* wihbf = (__hip_bfloat16*)(ws + wih_o);
  __half* xpart = (__half*)(ws + xpart_o);

  hipMemsetAsync(ws + hbuf_o, 0, 2 * (size_t)BB * HH * 2, stream);
  hipMemsetAsync(ws + cnt_o, 0, 256, stream);

  cvt_bf16_kernel<<<4096, 256, 0, stream>>>((const float4*)x, (short4v*)xbf, (long)(M * 512 / 4));
  cvt_bf16_kernel<<<256, 256, 0, stream>>>((const float4*)Wih, (short4v*)wihbf, (long)((size_t)GG * 512 / 4));

  gemm_xpart<<<16384, 256, 0, stream>>>(xbf, wihbf, bih, bhh, xpart);
  lstm_scan_kernel<<<32, 512, 0, stream>>>(xpart, Whh, (unsigned long long*)(ws + hbuf_o), outp,
                                           (unsigned*)(ws + cnt_o));
}

// Round 3
// 13321.707 us; speedup vs baseline: 1.6155x; 1.6155x over previous
//
#include <hip/hip_runtime.h>
#include <hip/hip_bf16.h>
#include <hip/hip_fp16.h>

#define TT 2048
#define BB 64
#define HH 512
#define GG 2048  // 4H

typedef __attribute__((ext_vector_type(4))) float f32x4;
typedef __attribute__((ext_vector_type(8))) short short8;
typedef __attribute__((ext_vector_type(4))) short short4v;
typedef __attribute__((ext_vector_type(4))) unsigned u32x4;

static __device__ __forceinline__ short f2bf(float f) {
  unsigned u = __builtin_bit_cast(unsigned, f);
  u = (u + 0x7FFFu + ((u >> 16) & 1u)) >> 16;
  return (short)u;
}
static __device__ __forceinline__ float fsigmoid(float x) { return 1.0f / (1.0f + __expf(-x)); }
static __device__ __forceinline__ float ftanh(float x) {
  float e = __expf(2.0f * x);
  return 1.0f - 2.0f / (e + 1.0f);
}
static __device__ __forceinline__ float h2f(unsigned short u) {
  __half h = __builtin_bit_cast(__half, u);
  return __half2float(h);
}

// ---------------- fp32 -> bf16 convert ----------------
__global__ void cvt_bf16_kernel(const float4* __restrict__ in, short4v* __restrict__ outp, long n4) {
  long i = (long)blockIdx.x * blockDim.x + threadIdx.x;
  long stride = (long)gridDim.x * blockDim.x;
  for (; i < n4; i += stride) {
    float4 v = in[i];
    short4v o;
    o[0] = f2bf(v.x); o[1] = f2bf(v.y); o[2] = f2bf(v.z); o[3] = f2bf(v.w);
    outp[i] = o;
  }
}

// ---------------- flag init at the coherence point (NOT memset: sc1 readers) ---------
__global__ void init_flags(unsigned* flags) {
  __hip_atomic_store(flags + threadIdx.x, 0u, __ATOMIC_RELAXED, __HIP_MEMORY_SCOPE_AGENT);
}

// ---------------- phase 1: xpart = X @ W_ih^T + (b_ih + b_hh), f16, scan layout -------
// out layout: [t (2048)][blk (32)][batch (64)][q*16+j (64)]  (q=gate, j=col-in-block)
__global__ __launch_bounds__(256) void gemm_xpart(
    const __hip_bfloat16* __restrict__ Abf, const __hip_bfloat16* __restrict__ Bbf,
    const float* __restrict__ bih, const float* __restrict__ bhh, __half* __restrict__ xout) {
  __shared__ __hip_bfloat16 As[128 * 64];
  __shared__ __hip_bfloat16 Bs[128 * 64];
  const int nwg = gridDim.x;
  const int bid = blockIdx.x;
  const int vb = (bid & 7) * (nwg >> 3) + (bid >> 3);
  const int mt = vb >> 4;
  const int nt = vb & 15;
  const size_t m0 = (size_t)mt * 128;
  const int n0 = nt * 128;
  const int tid = threadIdx.x;
  const int lane = tid & 63;
  const int w = tid >> 6;
  const int wm = w >> 1, wn = w & 1;
  const int g = lane >> 4;
  f32x4 acc[4][4] = {};
  for (int k0 = 0; k0 < 512; k0 += 64) {
#pragma unroll
    for (int i = 0; i < 4; i++) {
      const int slot = w * 4 + i;
      const int row = slot * 8 + (lane >> 3);
      const int segS = (lane & 7) ^ (row & 7);
      const __hip_bfloat16* ga = Abf + (m0 + row) * 512 + k0 + segS * 8;
      const __hip_bfloat16* gb = Bbf + (size_t)(n0 + row) * 512 + k0 + segS * 8;
      __builtin_amdgcn_global_load_lds(
          (const __attribute__((address_space(1))) unsigned*)(const void*)ga,
          (__attribute__((address_space(3))) unsigned*)(void*)(As + slot * 512), 16, 0, 0);
      __builtin_amdgcn_global_load_lds(
          (const __attribute__((address_space(1))) unsigned*)(const void*)gb,
          (__attribute__((address_space(3))) unsigned*)(void*)(Bs + slot * 512), 16, 0, 0);
    }
    __syncthreads();
#pragma unroll
    for (int kk = 0; kk < 2; kk++) {
      short8 av[4], bv[4];
#pragma unroll
      for (int f = 0; f < 4; f++) {
        const int row = wm * 64 + f * 16 + (lane & 15);
        av[f] = *(const short8*)(As + row * 64 + ((((kk << 2) + g) ^ (row & 7)) << 3));
      }
#pragma unroll
      for (int f = 0; f < 4; f++) {
        const int row = wn * 64 + f * 16 + (lane & 15);
        bv[f] = *(const short8*)(Bs + row * 64 + ((((kk << 2) + g) ^ (row & 7)) << 3));
      }
#pragma unroll
      for (int fi = 0; fi < 4; fi++)
#pragma unroll
        for (int fj = 0; fj < 4; fj++)
          acc[fi][fj] = __builtin_amdgcn_mfma_f32_16x16x32_bf16(av[fi], bv[fj], acc[fi][fj], 0, 0, 0);
    }
    __syncthreads();
  }
#pragma unroll
  for (int fj = 0; fj < 4; fj++) {
    const int n = n0 + wn * 64 + fj * 16 + (lane & 15);
    const float bias = bih[n] + bhh[n];
    const int q = n >> 9;
    const int bk = (n >> 4) & 31;
    const int j = n & 15;
#pragma unroll
    for (int fi = 0; fi < 4; fi++) {
      const size_t mrow = m0 + wm * 64 + fi * 16 + g * 4;
#pragma unroll
      for (int r = 0; r < 4; r++) {
        const size_t m = mrow + r;
        const size_t tt = m >> 6;
        const size_t b = m & 63;
        xout[((tt * 32 + bk) * 64 + b) * 64 + q * 16 + j] = __float2half(acc[fi][fj][r] + bias);
      }
    }
  }
}

// ---------------- phase 2: persistent LSTM scan ----------------
// 32 blocks x 512 threads. Per-block flags + wave0 poll + coherent (sc0 sc1) h exchange.
__global__ __launch_bounds__(512, 1) void lstm_scan_kernel(
    const __half* __restrict__ xpart, const float* __restrict__ Whh,
    unsigned long long* hbuf, float* __restrict__ outp, unsigned* flags) {
  __shared__ unsigned short xps[2][4096];  // [buf][batch(64)][8 chunks x 8 f16], chunk^=(b&7)
  const int blk = blockIdx.x;
  const int tid = threadIdx.x;
  const int lane = tid & 63;
  const int w = tid >> 6;
  const int b16 = lane & 15;
  const int g4 = lane >> 4;
  const int nt = w & 3;
  const int mtA = w >> 2;   // 0 or 1
  const int mtB = mtA + 2;  // 2 or 3
  const int batch = nt * 16 + b16;
  const int qr = b16 & 3;
  const int jj = b16 >> 2;
  const int colA = blk * 16 + mtA * 4 + g4;
  const int colB = blk * 16 + mtB * 4 + g4;

  // ---- one-time: W_hh slices -> registers (bf16 frags) ----
  const int rowA = qr * 512 + blk * 16 + mtA * 4 + jj;
  const int rowB = qr * 512 + blk * 16 + mtB * 4 + jj;
  short8 wA[16], wB[16];
#pragma unroll
  for (int kt = 0; kt < 16; kt++) {
    const float* pa = Whh + (size_t)rowA * 512 + kt * 32 + g4 * 8;
    const float* pb = Whh + (size_t)rowB * 512 + kt * 32 + g4 * 8;
    float4 a0 = *(const float4*)pa;
    float4 a1 = *(const float4*)(pa + 4);
    float4 b0 = *(const float4*)pb;
    float4 b1 = *(const float4*)(pb + 4);
    short8 va, vb;
    va[0] = f2bf(a0.x); va[1] = f2bf(a0.y); va[2] = f2bf(a0.z); va[3] = f2bf(a0.w);
    va[4] = f2bf(a1.x); va[5] = f2bf(a1.y); va[6] = f2bf(a1.z); va[7] = f2bf(a1.w);
    vb[0] = f2bf(b0.x); vb[1] = f2bf(b0.y); vb[2] = f2bf(b0.z); vb[3] = f2bf(b0.w);
    vb[4] = f2bf(b1.x); vb[5] = f2bf(b1.y); vb[6] = f2bf(b1.z); vb[7] = f2bf(b1.w);
    wA[kt] = va;
    wB[kt] = vb;
  }

  // ---- xpart staging: thread (sb, sch) -> one 16B chunk of [blk][sb] row ----
  const int sb = tid >> 3;
  const int sch = tid & 7;
  const int schS = sch ^ (sb & 7);
  char* xpsb = (char*)&xps[0][0];
  {  // prologue tile t=0
    const __half* src = xpart + (((size_t)0 * 32 + blk) << 12) + (sb << 6) + (sch << 3);
    short8 v = *(const short8*)(const void*)src;
    *(short8*)(xpsb + sb * 128 + schS * 16) = v;
  }
  __syncthreads();

  float cA = 0.f, cB = 0.f, hAv = 0.f, hBv = 0.f;

  for (int t = 0; t < TT; t++) {
    // 1. prefetch next xpart tile (contiguous 8KB/block stream)
    const int tn = (t + 1 < TT) ? (t + 1) : (TT - 1);
    const __half* src = xpart + (((size_t)tn * 32 + blk) << 12) + (sb << 6) + (sch << 3);
    short8 xv = *(const short8*)(const void*)src;

    f32x4 accA = {0.f, 0.f, 0.f, 0.f};
    f32x4 accB = {0.f, 0.f, 0.f, 0.f};
    if (t > 0) {
      // 2. wave0 polls per-block flags; rest wait at barrier
      if (w == 0) {
        unsigned f;
        do {
          f = __hip_atomic_load(flags + (lane & 31), __ATOMIC_RELAXED, __HIP_MEMORY_SCOPE_AGENT);
        } while (!__all((int)(f >= (unsigned)t)));
      }
      __syncthreads();
      // 3. coherent 16B h loads straight into B-frags
      const unsigned long long hb = (unsigned long long)(uintptr_t)hbuf +
                                    (unsigned long long)((t & 1) * 65536 + batch * 1024 + g4 * 16);
      u32x4 hv[16];
#pragma unroll
      for (int kt = 0; kt < 16; kt++) {
        unsigned long long a = hb + (unsigned long long)(kt * 64);
        asm volatile("global_load_dwordx4 %0, %1, off sc0 sc1" : "=v"(hv[kt]) : "v"(a));
      }
      asm volatile("s_waitcnt vmcnt(0)" ::: "memory");
      __builtin_amdgcn_sched_barrier(0);
      // 4. MFMA
#pragma unroll
      for (int kt = 0; kt < 16; kt++) {
        short8 hf = __builtin_bit_cast(short8, hv[kt]);
        accA = __builtin_amdgcn_mfma_f32_16x16x32_bf16(wA[kt], hf, accA, 0, 0, 0);
        accB = __builtin_amdgcn_mfma_f32_16x16x32_bf16(wB[kt], hf, accB, 0, 0, 0);
      }
    }

    // 5. pointwise; xpart from LDS (layout: chunk = q*2 + (col&15)>>3, byte = (col&7)*2)
    const char* xb = xpsb + (t & 1) * 8192 + batch * 128;
    const int bx = batch & 7;
    float xA[4], xB[4];
#pragma unroll
    for (int qq = 0; qq < 4; qq++) {
      unsigned short uA = *(const unsigned short*)(xb + (((qq * 2) ^ bx) << 4) + ((colA & 7) << 1));
      unsigned short uB = *(const unsigned short*)(xb + (((qq * 2 + 1) ^ bx) << 4) + ((colB & 7) << 1));
      xA[qq] = h2f(uA);
      xB[qq] = h2f(uB);
    }
    float iA = fsigmoid(accA[0] + xA[0]);
    float fA = fsigmoid(accA[1] + xA[1]);
    float gA = ftanh(accA[2] + xA[2]);
    float oA = fsigmoid(accA[3] + xA[3]);
    cA = fA * cA + iA * gA;
    hAv = oA * ftanh(cA);
    float iB = fsigmoid(accB[0] + xB[0]);
    float fB = fsigmoid(accB[1] + xB[1]);
    float gB = ftanh(accB[2] + xB[2]);
    float oB = fsigmoid(accB[3] + xB[3]);
    cB = fB * cB + iB * gB;
    hBv = oB * ftanh(cB);

    // 6. h_{t+1} stores FIRST (only these are on the release path)
    float hAp = __shfl_xor(hAv, 16, 64);
    float hBp = __shfl_xor(hBv, 16, 64);
    if ((g4 & 1) == 0) {
      unsigned* hd = (unsigned*)(hbuf + (size_t)((t + 1) & 1) * (BB * 128));
      unsigned pkA = (unsigned)(unsigned short)f2bf(hAv) | ((unsigned)(unsigned short)f2bf(hAp) << 16);
      unsigned pkB = (unsigned)(unsigned short)f2bf(hBv) | ((unsigned)(unsigned short)f2bf(hBp) << 16);
      __hip_atomic_store(hd + (size_t)batch * 256 + (colA >> 1), pkA, __ATOMIC_RELAXED, __HIP_MEMORY_SCOPE_AGENT);
      __hip_atomic_store(hd + (size_t)batch * 256 + (colB >> 1), pkB, __ATOMIC_RELAXED, __HIP_MEMORY_SCOPE_AGENT);
    }
    asm volatile("s_waitcnt vmcnt(0)" ::: "memory");

    // 7. commit prefetched xpart tile (other buffer; readers are past barrier B of next iter)
    *(short8*)(xpsb + ((t + 1) & 1) * 8192 + sb * 128 + schS * 16) = xv;

    // 8. barrier B: all waves' h-stores are at the coherence point -> signal
    __syncthreads();
    if (tid == 0)
      __hip_atomic_store(flags + blk, (unsigned)(t + 1), __ATOMIC_RELAXED, __HIP_MEMORY_SCOPE_AGENT);

    // 9. output stores drain in the shadow of the next poll
    float* od = outp + ((size_t)t * BB + batch) * HH;
    od[colA] = hAv;
    od[colB] = hBv;
  }

  // final (h_T, c_T)
  float* hT = outp + (size_t)TT * BB * HH;
  float* cT = hT + (size_t)BB * HH;
  hT[(size_t)batch * HH + colA] = hAv;
  hT[(size_t)batch * HH + colB] = hBv;
  cT[(size_t)batch * HH + colA] = cA;
  cT[(size_t)batch * HH + colB] = cB;
}

extern "C" void kernel_launch(void* const* d_in, const int* in_sizes, int n_in,
                              void* d_out, int out_size, void* d_ws, size_t ws_size,
                              hipStream_t stream) {
  (void)in_sizes; (void)n_in; (void)out_size; (void)ws_size;
  const float* x = (const float*)d_in[0];
  const float* Wih = (const float*)d_in[1];
  const float* Whh = (const float*)d_in[2];
  const float* bih = (const float*)d_in[3];
  const float* bhh = (const float*)d_in[4];
  float* outp = (float*)d_out;
  char* ws = (char*)d_ws;

  const size_t M = (size_t)TT * BB;  // 131072
  size_t off = 0;
  auto take = [&](size_t sz) { size_t r = off; off = (off + sz + 255) & ~255ULL; return r; };
  const size_t xbf_o = take(M * 512 * 2);
  const size_t wih_o = take((size_t)GG * 512 * 2);
  const size_t hbuf_o = take(2 * (size_t)BB * HH * 2);
  const size_t flg_o = take(256);
  const size_t xpart_o = take(M * (size_t)GG * 2);

  __hip_bfloat16* xbf = (__hip_bfloat16*)(ws + xbf_o);
  __hip_bfloat16* wihbf = (__hip_bfloat16*)(ws + wih_o);
  __half* xpart = (__half*)(ws + xpart_o);

  init_flags<<<1, 64, 0, stream>>>((unsigned*)(ws + flg_o));
  cvt_bf16_kernel<<<4096, 256, 0, stream>>>((const float4*)x, (short4v*)xbf, (long)(M * 512 / 4));
  cvt_bf16_kernel<<<256, 256, 0, stream>>>((const float4*)Wih, (short4v*)wihbf, (long)((size_t)GG * 512 / 4));

  gemm_xpart<<<16384, 256, 0, stream>>>(xbf, wihbf, bih, bhh, xpart);
  lstm_scan_kernel<<<32, 512, 0, stream>>>(xpart, Whh, (unsigned long long*)(ws + hbuf_o), outp,
                                           (unsigned*)(ws + flg_o));
}

// Round 4
// 8228.020 us; speedup vs baseline: 2.6157x; 1.6191x over previous
//
#include <hip/hip_runtime.h>
#include <hip/hip_bf16.h>
#include <hip/hip_fp16.h>

#define TT 2048
#define BB 64
#define HH 512
#define GG 2048  // 4H

typedef __attribute__((ext_vector_type(4))) float f32x4;
typedef __attribute__((ext_vector_type(8))) short short8;
typedef __attribute__((ext_vector_type(4))) short short4v;
typedef __attribute__((ext_vector_type(4))) unsigned u32x4;

static __device__ __forceinline__ short f2bf(float f) {
  unsigned u = __builtin_bit_cast(unsigned, f);
  u = (u + 0x7FFFu + ((u >> 16) & 1u)) >> 16;
  return (short)u;
}
static __device__ __forceinline__ float fsigmoid(float x) { return 1.0f / (1.0f + __expf(-x)); }
static __device__ __forceinline__ float ftanh(float x) {
  float e = __expf(2.0f * x);
  return 1.0f - 2.0f / (e + 1.0f);
}
static __device__ __forceinline__ float h2f(unsigned short u) {
  __half h = __builtin_bit_cast(__half, u);
  return __half2float(h);
}

// ---------------- fp32 -> bf16 convert ----------------
__global__ void cvt_bf16_kernel(const float4* __restrict__ in, short4v* __restrict__ outp, long n4) {
  long i = (long)blockIdx.x * blockDim.x + threadIdx.x;
  long stride = (long)gridDim.x * blockDim.x;
  for (; i < n4; i += stride) {
    float4 v = in[i];
    short4v o;
    o[0] = f2bf(v.x); o[1] = f2bf(v.y); o[2] = f2bf(v.z); o[3] = f2bf(v.w);
    outp[i] = o;
  }
}

// ---------------- flag init at the coherence point ----------------
__global__ void init_flags(unsigned* flags) {
  __hip_atomic_store(flags + threadIdx.x, 0u, __ATOMIC_RELAXED, __HIP_MEMORY_SCOPE_AGENT);
}

// ---------------- phase 1: xpart = X @ W_ih^T + (b_ih + b_hh), f16 ----------------
// out layout: [t][bg(4)][cp(16)][thread(256)][slot(2)*4 + gate(4)] f16 (16B per thread)
// thread = w*64 + g4*16 + b16 handles cells (batch bg*16+b16, col cp*32 + (w + 4*slot)*4 + g4)
__global__ __launch_bounds__(256) void gemm_xpart(
    const __hip_bfloat16* __restrict__ Abf, const __hip_bfloat16* __restrict__ Bbf,
    const float* __restrict__ bih, const float* __restrict__ bhh, __half* __restrict__ xout) {
  __shared__ __hip_bfloat16 As[128 * 64];
  __shared__ __hip_bfloat16 Bs[128 * 64];
  const int nwg = gridDim.x;
  const int bid = blockIdx.x;
  const int vb = (bid & 7) * (nwg >> 3) + (bid >> 3);
  const int mt = vb >> 4;
  const int nt = vb & 15;
  const size_t m0 = (size_t)mt * 128;
  const int n0 = nt * 128;
  const int tid = threadIdx.x;
  const int lane = tid & 63;
  const int w = tid >> 6;
  const int wm = w >> 1, wn = w & 1;
  const int g = lane >> 4;
  f32x4 acc[4][4] = {};
  for (int k0 = 0; k0 < 512; k0 += 64) {
#pragma unroll
    for (int i = 0; i < 4; i++) {
      const int slot = w * 4 + i;
      const int row = slot * 8 + (lane >> 3);
      const int segS = (lane & 7) ^ (row & 7);
      const __hip_bfloat16* ga = Abf + (m0 + row) * 512 + k0 + segS * 8;
      const __hip_bfloat16* gb = Bbf + (size_t)(n0 + row) * 512 + k0 + segS * 8;
      __builtin_amdgcn_global_load_lds(
          (const __attribute__((address_space(1))) unsigned*)(const void*)ga,
          (__attribute__((address_space(3))) unsigned*)(void*)(As + slot * 512), 16, 0, 0);
      __builtin_amdgcn_global_load_lds(
          (const __attribute__((address_space(1))) unsigned*)(const void*)gb,
          (__attribute__((address_space(3))) unsigned*)(void*)(Bs + slot * 512), 16, 0, 0);
    }
    __syncthreads();
#pragma unroll
    for (int kk = 0; kk < 2; kk++) {
      short8 av[4], bv[4];
#pragma unroll
      for (int f = 0; f < 4; f++) {
        const int row = wm * 64 + f * 16 + (lane & 15);
        av[f] = *(const short8*)(As + row * 64 + ((((kk << 2) + g) ^ (row & 7)) << 3));
      }
#pragma unroll
      for (int f = 0; f < 4; f++) {
        const int row = wn * 64 + f * 16 + (lane & 15);
        bv[f] = *(const short8*)(Bs + row * 64 + ((((kk << 2) + g) ^ (row & 7)) << 3));
      }
#pragma unroll
      for (int fi = 0; fi < 4; fi++)
#pragma unroll
        for (int fj = 0; fj < 4; fj++)
          acc[fi][fj] = __builtin_amdgcn_mfma_f32_16x16x32_bf16(av[fi], bv[fj], acc[fi][fj], 0, 0, 0);
    }
    __syncthreads();
  }
#pragma unroll
  for (int fj = 0; fj < 4; fj++) {
    const int n = n0 + wn * 64 + fj * 16 + (lane & 15);
    const float bias = bih[n] + bhh[n];
    const int q = n >> 9;        // gate
    const int hcol = n & 511;
    const int cpn = hcol >> 5;
    const int j = hcol & 31;
    const int wv = (j >> 2) & 3;
    const int g4v = j & 3;
    const int slot = j >> 4;
    const int thr = wv * 64 + g4v * 16;  // + b16 per element
#pragma unroll
    for (int fi = 0; fi < 4; fi++) {
      const size_t mrow = m0 + wm * 64 + fi * 16 + g * 4;
#pragma unroll
      for (int r = 0; r < 4; r++) {
        const size_t m = mrow + r;
        const size_t tt = m >> 6;
        const int bglob = (int)(m & 63);
        const int bgn = bglob >> 4;
        const int b16n = bglob & 15;
        const size_t idx = ((((tt * 4 + bgn) * 16 + cpn) * 256 + (size_t)(thr + b16n)) << 3) +
                           (size_t)(slot * 4 + q);
        xout[idx] = __float2half(acc[fi][fj][r] + bias);
      }
    }
  }
}

// ---------------- phase 2: persistent LSTM scan ----------------
// 64 blocks = [bg(4)][cp(16)] x 256 threads (4 waves). Block owns 16 batches x 32 h-cols.
// Per step: poll bg's 16 flags -> dense-stage bg's 16KB h (sc0 sc1) -> LDS (XOR-swizzled)
// -> ds_read B-frags -> 2 MFMA chains vs reg-resident W -> pointwise -> packed h stores
// (relaxed agent atomics) -> drain -> flag. Batch groups fully decoupled.
__global__ __launch_bounds__(256, 1) void lstm_scan_kernel(
    const __half* __restrict__ xpart, const float* __restrict__ Whh,
    char* hbuf, float* __restrict__ outp, unsigned* flags) {
  __shared__ char Hs[16384];  // [b(16)][seg(64) x 16B], seg stored at (seg ^ (b&7))
  const int blk = blockIdx.x;
  const int bg = blk >> 4;
  const int cp = blk & 15;
  const int tid = threadIdx.x;
  const int lane = tid & 63;
  const int w = tid >> 6;
  const int b16 = lane & 15;
  const int g4 = lane >> 4;
  const int qr = b16 & 3;   // A-frag row -> gate
  const int jj = b16 >> 2;  // A-frag row -> col-in-tile
  const int colA = cp * 32 + w * 4 + g4;
  const int colB = cp * 32 + (w + 4) * 4 + g4;
  const int batchg = bg * 16 + b16;

  // ---- one-time: W_hh slices -> registers (bf16 A-frags), tiles w and w+4 ----
  const int rowA = qr * 512 + cp * 32 + w * 4 + jj;
  const int rowB = qr * 512 + cp * 32 + (w + 4) * 4 + jj;
  short8 wA[16], wB[16];
#pragma unroll
  for (int kt = 0; kt < 16; kt++) {
    const float* pa = Whh + (size_t)rowA * 512 + kt * 32 + g4 * 8;
    const float* pb = Whh + (size_t)rowB * 512 + kt * 32 + g4 * 8;
    float4 a0 = *(const float4*)pa;
    float4 a1 = *(const float4*)(pa + 4);
    float4 b0 = *(const float4*)pb;
    float4 b1 = *(const float4*)(pb + 4);
    short8 va, vb;
    va[0] = f2bf(a0.x); va[1] = f2bf(a0.y); va[2] = f2bf(a0.z); va[3] = f2bf(a0.w);
    va[4] = f2bf(a1.x); va[5] = f2bf(a1.y); va[6] = f2bf(a1.z); va[7] = f2bf(a1.w);
    vb[0] = f2bf(b0.x); vb[1] = f2bf(b0.y); vb[2] = f2bf(b0.z); vb[3] = f2bf(b0.w);
    vb[4] = f2bf(b1.x); vb[5] = f2bf(b1.y); vb[6] = f2bf(b1.z); vb[7] = f2bf(b1.w);
    wA[kt] = va;
    wB[kt] = vb;
  }

  // xpart: 16B per thread per step, thread-linear
  const size_t xstride = (size_t)4 * 16 * 256 * 8;  // per-t elems
  const __half* xbase = xpart + ((size_t)bg * 16 + cp) * 256 * 8 + (size_t)tid * 8;
  short8 xv = *(const short8*)(const void*)xbase;  // t = 0

  // stage constants: this thread stages rows b = p*4+w (p=0..3), seg = lane
  const unsigned long long hroot = (unsigned long long)(uintptr_t)hbuf + (unsigned long long)(bg * 16384);

  float cA = 0.f, cB = 0.f, hAv = 0.f, hBv = 0.f;

  for (int t = 0; t < TT; t++) {
    // prefetch next step's xpart (plain cached load; consumed next iteration)
    const int tn = (t + 1 < TT) ? (t + 1) : (TT - 1);
    short8 xvn = *(const short8*)(const void*)(xbase + (size_t)tn * xstride);

    f32x4 accA = {0.f, 0.f, 0.f, 0.f};
    f32x4 accB = {0.f, 0.f, 0.f, 0.f};
    if (t > 0) {
      // poll: wave0 watches this bg's 16 flags (one 64B line)
      if (w == 0) {
        unsigned f;
        do {
          f = __hip_atomic_load(flags + bg * 16 + (lane & 15), __ATOMIC_RELAXED, __HIP_MEMORY_SCOPE_AGENT);
        } while (!__all((int)(f >= (unsigned)t)));
      }
      __syncthreads();
      // stage 16KB h (dense, coherent) -> regs
      const unsigned long long hb = hroot + (unsigned long long)((t & 1) * 65536);
      u32x4 hv[4];
#pragma unroll
      for (int p = 0; p < 4; p++) {
        const unsigned long long a = hb + (unsigned long long)((p * 4 + w) * 1024 + lane * 16);
        asm volatile("global_load_dwordx4 %0, %1, off sc0 sc1" : "=v"(hv[p]) : "v"(a));
      }
      asm volatile("s_waitcnt vmcnt(0)" ::: "memory");
      __builtin_amdgcn_sched_barrier(0);
      // regs -> LDS (XOR seg-swizzle; b128 writes are 2-way per quarter-wave = free)
#pragma unroll
      for (int p = 0; p < 4; p++) {
        const int b = p * 4 + w;
        *(u32x4*)(Hs + b * 1024 + ((lane ^ (b & 7)) << 4)) = hv[p];
      }
      __syncthreads();
      // MFMA: B-frag = h[b16][kt*32 + g4*8 ..+8] from swizzled LDS; shared by both chains
#pragma unroll
      for (int kt = 0; kt < 16; kt++) {
        const int sp = ((kt * 4 + g4) ^ (b16 & 7));
        short8 hf = *(const short8*)(Hs + b16 * 1024 + (sp << 4));
        accA = __builtin_amdgcn_mfma_f32_16x16x32_bf16(wA[kt], hf, accA, 0, 0, 0);
        accB = __builtin_amdgcn_mfma_f32_16x16x32_bf16(wB[kt], hf, accB, 0, 0, 0);
      }
    }

    // pointwise: xv = [cellA gates i,f,g,o | cellB gates i,f,g,o]
    float iA = fsigmoid(accA[0] + h2f((unsigned short)xv[0]));
    float fA = fsigmoid(accA[1] + h2f((unsigned short)xv[1]));
    float gA = ftanh(accA[2] + h2f((unsigned short)xv[2]));
    float oA = fsigmoid(accA[3] + h2f((unsigned short)xv[3]));
    cA = fA * cA + iA * gA;
    hAv = oA * ftanh(cA);
    float iB = fsigmoid(accB[0] + h2f((unsigned short)xv[4]));
    float fB = fsigmoid(accB[1] + h2f((unsigned short)xv[5]));
    float gB = ftanh(accB[2] + h2f((unsigned short)xv[6]));
    float oB = fsigmoid(accB[3] + h2f((unsigned short)xv[7]));
    cB = fB * cB + iB * gB;
    hBv = oB * ftanh(cB);

    // h_{t+1} stores (release path): pack col pairs via shfl, g4-even lanes store dwords
    float hAp = __shfl_xor(hAv, 16, 64);
    float hBp = __shfl_xor(hBv, 16, 64);
    if ((g4 & 1) == 0) {
      unsigned* hd = (unsigned*)(hbuf + ((t + 1) & 1) * 65536 + bg * 16384 + b16 * 1024);
      unsigned pkA = (unsigned)(unsigned short)f2bf(hAv) | ((unsigned)(unsigned short)f2bf(hAp) << 16);
      unsigned pkB = (unsigned)(unsigned short)f2bf(hBv) | ((unsigned)(unsigned short)f2bf(hBp) << 16);
      __hip_atomic_store(hd + (colA >> 1), pkA, __ATOMIC_RELAXED, __HIP_MEMORY_SCOPE_AGENT);
      __hip_atomic_store(hd + (colB >> 1), pkB, __ATOMIC_RELAXED, __HIP_MEMORY_SCOPE_AGENT);
    }
    asm volatile("s_waitcnt vmcnt(0)" ::: "memory");
    __syncthreads();
    if (tid == 0)
      __hip_atomic_store(flags + bg * 16 + cp, (unsigned)(t + 1), __ATOMIC_RELAXED, __HIP_MEMORY_SCOPE_AGENT);

    // outputs drain in the shadow of the next poll
    float* od = outp + ((size_t)t * BB + batchg) * HH;
    od[colA] = hAv;
    od[colB] = hBv;
    xv = xvn;
  }

  // final (h_T, c_T)
  float* hT = outp + (size_t)TT * BB * HH;
  float* cT = hT + (size_t)BB * HH;
  hT[(size_t)batchg * HH + colA] = hAv;
  hT[(size_t)batchg * HH + colB] = hBv;
  cT[(size_t)batchg * HH + colA] = cA;
  cT[(size_t)batchg * HH + colB] = cB;
}

extern "C" void kernel_launch(void* const* d_in, const int* in_sizes, int n_in,
                              void* d_out, int out_size, void* d_ws, size_t ws_size,
                              hipStream_t stream) {
  (void)in_sizes; (void)n_in; (void)out_size; (void)ws_size;
  const float* x = (const float*)d_in[0];
  const float* Wih = (const float*)d_in[1];
  const float* Whh = (const float*)d_in[2];
  const float* bih = (const float*)d_in[3];
  const float* bhh = (const float*)d_in[4];
  float* outp = (float*)d_out;
  char* ws = (char*)d_ws;

  const size_t M = (size_t)TT * BB;  // 131072
  size_t off = 0;
  auto take = [&](size_t sz) { size_t r = off; off = (off + sz + 255) & ~255ULL; return r; };
  const size_t xbf_o = take(M * 512 * 2);
  const size_t wih_o = take((size_t)GG * 512 * 2);
  const size_t hbuf_o = take(2 * 65536);
  const size_t flg_o = take(256);
  const size_t xpart_o = take(M * (size_t)GG * 2);

  __hip_bfloat16* xbf = (__hip_bfloat16*)(ws + xbf_o);
  __hip_bfloat16* wihbf = (__hip_bfloat16*)(ws + wih_o);
  __half* xpart = (__half*)(ws + xpart_o);

  hipMemsetAsync(ws + hbuf_o, 0, 2 * 65536, stream);
  init_flags<<<1, 64, 0, stream>>>((unsigned*)(ws + flg_o));
  cvt_bf16_kernel<<<4096, 256, 0, stream>>>((const float4*)x, (short4v*)xbf, (long)(M * 512 / 4));
  cvt_bf16_kernel<<<256, 256, 0, stream>>>((const float4*)Wih, (short4v*)wihbf, (long)((size_t)GG * 512 / 4));

  gemm_xpart<<<16384, 256, 0, stream>>>(xbf, wihbf, bih, bhh, xpart);
  lstm_scan_kernel<<<64, 256, 0, stream>>>(xpart, Whh, ws + hbuf_o, outp, (unsigned*)(ws + flg_o));
}